// Round 19
// baseline (627.736 us; speedup 1.0000x reference)
//
#include <hip/hip_runtime.h>
#include <hip/hip_bf16.h>
#include <math.h>

#define HH 384
#define WW 384
#define NPIX (HH*WW)        // 147456
#define BB 2
#define CC 16
#define NKF 9437184         // pred_kspace float count

__device__ inline float2 cmul(float2 a, float2 b) {
    return make_float2(a.x*b.x - a.y*b.y, a.x*b.y + a.y*b.x);
}
__device__ inline float bf2f(unsigned short u) {
    union { unsigned int i; float f; } c; c.i = ((unsigned)u) << 16; return c.f;
}
__device__ inline float2 loadc2(const void* p, int dt, size_t i) {
    if (dt == 1) { ushort2 u = ((const ushort2*)p)[i];
        return make_float2(bf2f(u.x), bf2f(u.y)); }
    if (dt == 2) { double2 d = ((const double2*)p)[i];
        return make_float2((float)d.x, (float)d.y); }
    return ((const float2*)p)[i];
}
__device__ inline float loads1(const void* p, int dt, size_t i) {
    if (dt == 1) return bf2f(((const unsigned short*)p)[i]);
    if (dt == 2) return (float)((const double*)p)[i];
    return ((const float*)p)[i];
}
__device__ inline int flex_int1(const void* p) {
    unsigned v = ((const unsigned*)p)[0];
    if (v < 1000000u) return (int)v;
    float f = ((const float*)p)[0];
    if (f > -1e6f && f < 1e6f && f == floorf(f)) return (int)f;
    return (int)((const double*)p)[0];
}
__device__ inline int flex_int_arr(const void* p, int i) {
    const unsigned* u = (const unsigned*)p;
    if (u[1] == 0u && u[3] == 0u) return (int)u[2*i];   // int64
    if (u[0] >= 1u && u[0] < 1000000u) return (int)u[i];// int32
    float f = ((const float*)p)[i];
    if (f > -1e6f && f < 1e6f) return (int)f;
    return (int)((const double*)p)[i];
}

// input float-dtype detect (HW-confirmed f32; kept for robustness)
__global__ void detect_dtype(const unsigned* __restrict__ q, int* dt)
{
    __shared__ int bad, sig;
    if (threadIdx.x == 0) { bad = 0; sig = 0; }
    __syncthreads();
    const unsigned short* q16 = (const unsigned short*)q;
    int mybad = 0, mysig = 0;
    for (int i = threadIdx.x; i < 8192; i += 256) {
        unsigned short u = q16[i];
        int e = (u >> 7) & 0xFF;
        if (!(e == 0 || (e >= 100 && e <= 140))) mybad++;
    }
    for (int i = threadIdx.x; i < 2048; i += 256) {
        unsigned hi = q[2*i + 1];
        int e = (hi >> 20) & 0x7FF;
        if (e >= 1003 && e <= 1040) mysig++;
    }
    atomicAdd(&bad, mybad);
    atomicAdd(&sig, mysig);
    __syncthreads();
    if (threadIdx.x == 0)
        *dt = (bad < 400) ? 1 : ((sig > 1950) ? 2 : 0);
}

// ---------------------------------------------------------------------------
// FFT-384 (3 x radix-2 DIF FFT-128 + radix-3 DIT combine); fftshift pair
// folded as (-1)^n input / (-1)^u output sign; ortho 1/sqrt(384).
// HW-verified vs double-precision direct DFT (round-9 oracle). In-place safe.
// ---------------------------------------------------------------------------
#define NLINE 8
#define SP 385

template<int DIR, int AXIS>
__global__ __launch_bounds__(256)
void fft384(const void* in, float2* out, const int* DTp, int srcExt)
{
    __shared__ float2 tw[384];
    __shared__ float2 stage[NLINE * SP];
    __shared__ float2 work[4][384];
    const int tid = threadIdx.x;
    const int dt = srcExt ? *DTp : 0;
    for (int j = tid; j < 384; j += 256) {
        float s, c;
        sincosf(-6.283185307179586f * (float)j / 384.0f, &s, &c);
        tw[j] = make_float2(c, s);
    }
    const int img = blockIdx.x / 48;
    const int t0  = (blockIdx.x % 48) * NLINE;
    const size_t base = (size_t)img * NPIX;
    float2* dst = out + base;
    if (AXIS == 0) {
        for (int f = tid; f < NLINE*384; f += 256) {
            int l = f / 384, n = f - l*384;
            stage[l*SP + n] = loadc2(in, dt, base + (size_t)(t0 + l)*384 + n);
        }
    } else {
        for (int f = tid; f < NLINE*384; f += 256) {
            int l = f & 7, n = f >> 3;
            stage[l*SP + n] = loadc2(in, dt, base + (size_t)n*384 + (t0 + l));
        }
    }
    __syncthreads();
    const int g    = tid >> 6;
    const int lane = tid & 63;
    float2* w = work[g];
    const float SCALE = 0.05103103630798288f;
    for (int it = 0; it < 2; ++it) {
        const int l = it*4 + g;
        #pragma unroll
        for (int m = 0; m < 6; ++m) {
            int n = lane + 64*m;
            float2 v = stage[l*SP + n];
            float sgn = (n & 1) ? -1.f : 1.f;
            int q = n / 3;
            int r3 = n - 3*q;
            w[r3*128 + q] = make_float2(v.x*sgn, v.y*sgn);
        }
        __syncthreads();
        #pragma unroll
        for (int s = 0; s < 7; ++s) {
            const int h = 64 >> s;
            const int tstep = 3 << s;
            const int j = lane & (h-1);
            const int i = ((lane & ~(h-1)) << 1) | j;
            float2 t = tw[j * tstep];
            if (DIR < 0) t.y = -t.y;
            #pragma unroll
            for (int n1 = 0; n1 < 3; ++n1) {
                float2* a = w + (n1 << 7);
                float2 u = a[i], v = a[i+h];
                float2 d = make_float2(u.x - v.x, u.y - v.y);
                a[i]   = make_float2(u.x + v.x, u.y + v.y);
                a[i+h] = cmul(d, t);
            }
            __syncthreads();
        }
        #pragma unroll
        for (int half = 0; half < 2; ++half) {
            int k2 = lane + 64*half;
            int r  = __brev((unsigned)k2) >> 25;
            float2 a0 = w[r], a1 = w[128 + r], a2 = w[256 + r];
            float2 t1 = tw[k2];
            float2 t2 = tw[(2*k2) % 384];
            float2 w3 = tw[128], w3b = tw[256];
            if (DIR < 0) { t1.y=-t1.y; t2.y=-t2.y; w3.y=-w3.y; w3b.y=-w3b.y; }
            float2 b1 = cmul(a1, t1), b2 = cmul(a2, t2);
            float2 X0 = make_float2(a0.x + b1.x + b2.x, a0.y + b1.y + b2.y);
            float2 c1 = cmul(w3, b1), c2 = cmul(w3b, b2);
            float2 X1 = make_float2(a0.x + c1.x + c2.x, a0.y + c1.y + c2.y);
            float2 d1 = cmul(w3b, b1), d2 = cmul(w3, b2);
            float2 X2 = make_float2(a0.x + d1.x + d2.x, a0.y + d1.y + d2.y);
            float sc = (k2 & 1) ? -SCALE : SCALE;
            stage[l*SP + k2      ] = make_float2(X0.x*sc, X0.y*sc);
            stage[l*SP + k2 + 128] = make_float2(X1.x*sc, X1.y*sc);
            stage[l*SP + k2 + 256] = make_float2(X2.x*sc, X2.y*sc);
        }
        __syncthreads();
    }
    if (AXIS == 0) {
        for (int f = tid; f < NLINE*384; f += 256) {
            int l = f / 384, n = f - l*384;
            dst[(size_t)(t0 + l)*384 + n] = stage[l*SP + n];
        }
    } else {
        for (int f = tid; f < NLINE*384; f += 256) {
            int l = f & 7, n = f >> 3;
            dst[(size_t)n*384 + (t0 + l)] = stage[l*SP + n];
        }
    }
}

// mask dtype classifier: 0=byte 2=32-bit 3=64-bit 4=16-bit (HW: FLAG=2 int32)
__global__ void detect_mask(const unsigned char* __restrict__ m, int* flag)
{
    __shared__ int sA, sB, sC, sD, sE;
    if (threadIdx.x == 0) { sA = sB = sC = sD = sE = 0; }
    __syncthreads();
    for (int i = threadIdx.x; i < 768; i += 256) {
        unsigned char v = m[i];
        if (v > 1) atomicOr(&sA, 1);
        if ((i & 3) && v) atomicOr(&sB, 1);
    }
    const unsigned short* m16 = (const unsigned short*)m;
    for (int i = threadIdx.x; i < 384; i += 256)
        if (!(i & 1) && m16[i]) atomicOr(&sC, 1);
    const unsigned int* m32 = (const unsigned int*)m;
    for (int i = threadIdx.x; i < 192; i += 256) {
        if ((i & 1) && m32[i]) atomicOr(&sD, 1);
        if (!(i & 1) && m32[i]) atomicOr(&sE, 1);
    }
    __syncthreads();
    if (threadIdx.x == 0) {
        int f;
        if (!sA) { if (sB) f = 0; else if (sD) f = 2; else f = 3; }
        else     { if (sC) f = 4; else if (sE) f = 2; else f = 3; }
        *flag = f;
    }
}

__device__ inline int read_mask(const void* m, int flag, int i)
{
    switch (flag) {
        case 0:  return ((const unsigned char*)m)[i] != 0;
        case 4:  return ((const unsigned short*)m)[i] != 0;
        case 3:  return ((const unsigned long long*)m)[i] != 0ULL;
        default: return ((const unsigned int*)m)[i] != 0u;
    }
}

__global__ __launch_bounds__(256)
void reduce_sens(const float2* __restrict__ xin, const void* __restrict__ sens,
                 float2* __restrict__ ximg, const int* DTp)
{
    const int dt = *DTp;
    const int b = blockIdx.y;
    const int p = blockIdx.x*256 + threadIdx.x;
    float2 acc = make_float2(0.f, 0.f);
    for (int c = 0; c < CC; ++c) {
        size_t o = ((size_t)(b*CC + c))*NPIX + p;
        float2 a = xin[o];
        float2 s = loadc2(sens, dt, o);
        acc.x += a.x*s.x + a.y*s.y;     // x * conj(s)
        acc.y += a.y*s.x - a.x*s.y;
    }
    ximg[(size_t)b*NPIX + p] = acc;
}

__global__ __launch_bounds__(256)
void stats_kernel(const float2* __restrict__ ximg, float* __restrict__ ms)
{
    const int b = blockIdx.x;
    const int tid = threadIdx.x;
    float sx=0.f, sy=0.f, qx=0.f, qy=0.f;
    for (int p = tid; p < NPIX; p += 256) {
        float2 v = ximg[(size_t)b*NPIX + p];
        sx += v.x; sy += v.y; qx += v.x*v.x; qy += v.y*v.y;
    }
    __shared__ float r0[256], r1[256], r2[256], r3[256];
    r0[tid]=sx; r1[tid]=sy; r2[tid]=qx; r3[tid]=qy;
    __syncthreads();
    for (int s = 128; s > 0; s >>= 1) {
        if (tid < s) {
            r0[tid]+=r0[tid+s]; r1[tid]+=r1[tid+s];
            r2[tid]+=r2[tid+s]; r3[tid]+=r3[tid+s];
        }
        __syncthreads();
    }
    if (tid == 0) {
        const float N = (float)NPIX;
        float var0 = (r2[0] - r0[0]*r0[0]/N) / (N - 1.f);
        float var1 = (r3[0] - r1[0]*r1[0]/N) / (N - 1.f);
        ms[(b*2+0)*2]   = r0[0]/N;
        ms[(b*2+0)*2+1] = sqrtf(var0);
        ms[(b*2+1)*2]   = r1[0]/N;
        ms[(b*2+1)*2+1] = sqrtf(var1);
    }
}

// fused: xn=(x-mean)/std ; h=relu(conv1(xn)) ; y=conv2(h)*std+mean
__global__ __launch_bounds__(256)
void conv_fused(const float2* __restrict__ ximg, const void* __restrict__ w1g,
                const void* __restrict__ b1g, const void* __restrict__ w2g,
                const void* __restrict__ b2g, const float* __restrict__ msg,
                float2* __restrict__ rim, const int* DTp)
{
    __shared__ float in0[20][21];
    __shared__ float in1[20][21];
    __shared__ float hid[18][19];
    __shared__ float w1s[1152];
    __shared__ float w2s[1152];
    __shared__ float b1s[64];
    const int dt = *DTp;
    const int b = blockIdx.z, bx = blockIdx.x, by = blockIdx.y;
    const int tid = threadIdx.x;
    for (int f = tid; f < 1152; f += 256) {
        w1s[f] = loads1(w1g, dt, f);
        w2s[f] = loads1(w2g, dt, f);
    }
    if (tid < 64) b1s[tid] = loads1(b1g, dt, tid);
    const float mean0 = msg[(b*2+0)*2], istd0 = 1.f/msg[(b*2+0)*2+1];
    const float mean1 = msg[(b*2+1)*2], istd1 = 1.f/msg[(b*2+1)*2+1];
    for (int f = tid; f < 400; f += 256) {
        int yy = f / 20, xx = f - yy*20;
        int gy = by*16 + yy - 2, gx = bx*16 + xx - 2;
        float a = 0.f, c = 0.f;
        if (gy >= 0 && gy < HH && gx >= 0 && gx < WW) {
            float2 v = ximg[(size_t)b*NPIX + gy*WW + gx];
            a = (v.x - mean0)*istd0;
            c = (v.y - mean1)*istd1;
        }
        in0[yy][xx] = a; in1[yy][xx] = c;
    }
    __syncthreads();
    const int tx = tid & 15, ty = tid >> 4;
    float acc0 = loads1(b2g, dt, 0), acc1 = loads1(b2g, dt, 1);
    for (int o = 0; o < 64; ++o) {
        for (int f = tid; f < 324; f += 256) {
            int yy = f / 18, xx = f - yy*18;
            int gy = by*16 + yy - 1, gx = bx*16 + xx - 1;
            float acc = b1s[o];
            const float* wv = &w1s[o*18];
            #pragma unroll
            for (int k = 0; k < 9; ++k) {
                acc += wv[k]   * in0[yy + k/3][xx + k%3];
                acc += wv[9+k] * in1[yy + k/3][xx + k%3];
            }
            hid[yy][xx] = (gy >= 0 && gy < HH && gx >= 0 && gx < WW)
                        ? fmaxf(acc, 0.f) : 0.f;
        }
        __syncthreads();
        const float* wa = &w2s[o*9];
        const float* wb = &w2s[576 + o*9];
        #pragma unroll
        for (int k = 0; k < 9; ++k) {
            float h = hid[ty + k/3][tx + k%3];
            acc0 += wa[k]*h;
            acc1 += wb[k]*h;
        }
        __syncthreads();
    }
    const float std0 = msg[(b*2+0)*2+1], std1 = msg[(b*2+1)*2+1];
    rim[(size_t)b*NPIX + (by*16+ty)*WW + (bx*16+tx)]
        = make_float2(acc0*std0 + mean0, acc1*std1 + mean1);
}

__global__ __launch_bounds__(256)
void expand_mul(const float2* __restrict__ rim, const void* __restrict__ sens,
                float2* __restrict__ out, const int* DTp)
{
    const int dt = *DTp;
    size_t idx = (size_t)blockIdx.x*256 + threadIdx.x;
    int bc = (int)(idx / NPIX);
    int b  = bc >> 4;
    int p  = (int)(idx - (size_t)bc*NPIX);
    out[idx] = cmul(rim[(size_t)b*NPIX + p], loadc2(sens, dt, idx));
}

// DC in-place on kf; ALSO writes pred_kspace to d_out as FLOAT32
__global__ __launch_bounds__(256)
void dc_kernel(float2* kf, const void* __restrict__ target,
               const void* __restrict__ mask, const int* __restrict__ flag,
               const void* __restrict__ dcw,
               float2* __restrict__ outk, const int* DTp)
{
    const int dt = *DTp;
    size_t idx = (size_t)blockIdx.x*256 + threadIdx.x;  // complex elements
    int p = (int)(idx % NPIX);
    int w = p % WW;
    int b = (int)(idx / ((size_t)CC*NPIX));
    int m = read_mask(mask, *flag, b*WW + w);
    float2 v = kf[idx];
    if (m) {
        float dw = loads1(dcw, dt, 0);
        float2 r = loadc2(target, dt, idx);
        v.x -= (v.x - r.x)*dw;
        v.y -= (v.y - r.y)*dw;
    }
    kf[idx] = v;
    outk[idx] = v;            // FLOAT32 output
}

// mean over h, logits, softmax over w; prob to ws (f32) + f32 out
__global__ __launch_bounds__(384)
void predictor(const float2* __restrict__ kimg, const void* __restrict__ wmp,
               const void* __restrict__ bmp, float* __restrict__ prob,
               float* __restrict__ outp, const int* DTp)
{
    const int dt = *DTp;
    const int b = blockIdx.x, w = threadIdx.x;
    float s0 = 0.f, s1 = 0.f;
    for (int h = 0; h < HH; ++h) {
        float2 v = kimg[((size_t)b*HH + h)*WW + w];
        s0 += v.x; s1 += v.y;
    }
    float logit = (s0*loads1(wmp,dt,0) + s1*loads1(wmp,dt,1)) * (1.0f/384.0f)
                + loads1(bmp,dt,0);
    __shared__ float red[8];
    float m = logit;
    for (int o = 32; o > 0; o >>= 1) m = fmaxf(m, __shfl_down(m, o, 64));
    int wid = w >> 6, lane = w & 63;
    if (lane == 0) red[wid] = m;
    __syncthreads();
    if (w == 0) { float mm = red[0]; for (int i = 1; i < 6; ++i) mm = fmaxf(mm, red[i]); red[6] = mm; }
    __syncthreads();
    m = red[6];
    float e = expf(logit - m);
    float s = e;
    for (int o = 32; o > 0; o >>= 1) s += __shfl_down(s, o, 64);
    __syncthreads();
    if (lane == 0) red[wid] = s;
    __syncthreads();
    if (w == 0) { float ss = 0.f; for (int i = 0; i < 6; ++i) ss += red[i]; red[7] = ss; }
    __syncthreads();
    float pr = e / red[7];
    prob[b*WW + w] = pr;
    outp[b*WW + w] = pr;      // FLOAT32 output
}

// top-k selection via stable descending rank; f32 out
__global__ __launch_bounds__(384)
void update_mask_k(const float* __restrict__ prob, const void* __restrict__ cmask,
                   const void* __restrict__ add_list, const void* __restrict__ itp,
                   float* __restrict__ outm, const int* DTp)
{
    const int dt = *DTp;
    const int b = blockIdx.x, w = threadIdx.x;
    __shared__ float p[384];
    float cm = loads1(cmask, dt, b*WW + w);
    float pv = prob[b*WW + w] * (1.0f - cm);
    p[w] = pv;
    __syncthreads();
    int rank = 0;
    for (int i = 0; i < 384; ++i) {
        float q = p[i];
        rank += (q > pv) || (q == pv && i < w);
    }
    int it = flex_int1(itp);
    if (it < 0 || it > 7) it = 0;
    int addn = flex_int_arr(add_list, b*8 + it);
    float val = cm + ((rank < addn) ? 1.0f : 0.0f);
    outm[b*WW + w] = val;     // FLOAT32 output
}

// ---------------------------------------------------------------------------
extern "C" void kernel_launch(void* const* d_in, const int* in_sizes, int n_in,
                              void* d_out, int out_size, void* d_ws, size_t ws_size,
                              hipStream_t stream)
{
    const void* src  = d_in[0];   // current_kspace
    const void* tgt  = d_in[1];   // ref_kspace
    const void* mask = d_in[2];
    const void* sens = d_in[3];
    const void* itp  = d_in[4];
    const void* cmask= d_in[5];
    const void* addl = d_in[7];
    const void* dcw  = d_in[8];
    const void* w1   = d_in[9];
    const void* b1   = d_in[10];
    const void* w2   = d_in[11];
    const void* b2   = d_in[12];
    const void* wmp  = d_in[13];
    const void* bmp  = d_in[14];
    float* out = (float*)d_out;   // FLOAT32 output buffer (round-18 verdict)

    float* ws = (float*)d_ws;
    const size_t OFF_XIMG = 9437184;
    const size_t OFF_RIM  = OFF_XIMG + 589824;
    const size_t OFF_MS   = OFF_RIM  + 589824;
    const size_t OFF_PROB = OFF_MS + 8;
    const size_t OFF_FLAG = OFF_PROB + 768;
    const size_t OFF_DT   = OFF_FLAG + 4;

    float2* A    = (float2*)ws;
    float2* XIMG = (float2*)(ws + OFF_XIMG);
    float2* RIM  = (float2*)(ws + OFF_RIM);
    float*  MS   = ws + OFF_MS;
    float*  PROB = ws + OFF_PROB;
    int*    FLAG = (int*)(ws + OFF_FLAG);
    int*    DT   = (int*)(ws + OFF_DT);

    const int gBig   = (BB*CC)*48;
    const int gSmall = BB*48;
    const int gElem  = (BB*CC*NPIX)/256;

    detect_dtype<<<1, 256, 0, stream>>>((const unsigned*)src, DT);
    detect_mask<<<1, 256, 0, stream>>>((const unsigned char*)mask, FLAG);

    // sens_reduce(current_kspace): ifft2c then sum x*conj(s)
    fft384<-1,0><<<gBig, 256, 0, stream>>>(src, A, DT, 1);
    fft384<-1,1><<<gBig, 256, 0, stream>>>(A, A, DT, 0);
    reduce_sens<<<dim3((NPIX/256), BB), 256, 0, stream>>>(A, sens, XIMG, DT);
    stats_kernel<<<BB, 256, 0, stream>>>(XIMG, MS);

    // apply_model
    conv_fused<<<dim3(24,24,BB), 256, 0, stream>>>(XIMG, w1, b1, w2, b2, MS, RIM, DT);

    // sens_expand -> model_term in A
    expand_mul<<<gElem, 256, 0, stream>>>(RIM, sens, A, DT);
    fft384<1,0><<<gBig, 256, 0, stream>>>(A, A, DT, 0);
    fft384<1,1><<<gBig, 256, 0, stream>>>(A, A, DT, 0);

    // data consistency in-place on A; f32 pred_kspace to d_out
    dc_kernel<<<gElem, 256, 0, stream>>>(A, tgt, mask, FLAG, dcw, (float2*)out, DT);

    // sens_reduce(pred_kspace)
    fft384<-1,0><<<gBig, 256, 0, stream>>>(A, A, DT, 0);
    fft384<-1,1><<<gBig, 256, 0, stream>>>(A, A, DT, 0);
    reduce_sens<<<dim3((NPIX/256), BB), 256, 0, stream>>>(A, sens, XIMG, DT);

    // kim = fft2c(restore_im_dc[:,0])
    fft384<1,0><<<gSmall, 256, 0, stream>>>(XIMG, XIMG, DT, 0);
    fft384<1,1><<<gSmall, 256, 0, stream>>>(XIMG, XIMG, DT, 0);

    // mask predictor + mask update (both FLOAT32 outputs)
    predictor<<<BB, 384, 0, stream>>>(XIMG, wmp, bmp, PROB, out + 9437184 + 768, DT);
    update_mask_k<<<BB, 384, 0, stream>>>(PROB, cmask, addl, itp, out + 9437184, DT);
}

// Round 20
// 563.108 us; speedup vs baseline: 1.1148x; 1.1148x over previous
//
#include <hip/hip_runtime.h>
#include <hip/hip_bf16.h>
#include <math.h>

#define HH 384
#define WW 384
#define NPIX (HH*WW)        // 147456
#define BB 2
#define CC 16
#define NKF 9437184         // pred_kspace float count

__device__ inline float2 cmul(float2 a, float2 b) {
    return make_float2(a.x*b.x - a.y*b.y, a.x*b.y + a.y*b.x);
}
__device__ inline float bf2f(unsigned short u) {
    union { unsigned int i; float f; } c; c.i = ((unsigned)u) << 16; return c.f;
}
__device__ inline float2 loadc2(const void* p, int dt, size_t i) {
    if (dt == 1) { ushort2 u = ((const ushort2*)p)[i];
        return make_float2(bf2f(u.x), bf2f(u.y)); }
    if (dt == 2) { double2 d = ((const double2*)p)[i];
        return make_float2((float)d.x, (float)d.y); }
    return ((const float2*)p)[i];
}
__device__ inline float loads1(const void* p, int dt, size_t i) {
    if (dt == 1) return bf2f(((const unsigned short*)p)[i]);
    if (dt == 2) return (float)((const double*)p)[i];
    return ((const float*)p)[i];
}
__device__ inline int flex_int1(const void* p) {
    unsigned v = ((const unsigned*)p)[0];
    if (v < 1000000u) return (int)v;
    float f = ((const float*)p)[0];
    if (f > -1e6f && f < 1e6f && f == floorf(f)) return (int)f;
    return (int)((const double*)p)[0];
}
__device__ inline int flex_int_arr(const void* p, int i) {
    const unsigned* u = (const unsigned*)p;
    if (u[1] == 0u && u[3] == 0u) return (int)u[2*i];   // int64
    if (u[0] >= 1u && u[0] < 1000000u) return (int)u[i];// int32
    float f = ((const float*)p)[i];
    if (f > -1e6f && f < 1e6f) return (int)f;
    return (int)((const double*)p)[i];
}

__global__ void detect_dtype(const unsigned* __restrict__ q, int* dt)
{
    __shared__ int bad, sig;
    if (threadIdx.x == 0) { bad = 0; sig = 0; }
    __syncthreads();
    const unsigned short* q16 = (const unsigned short*)q;
    int mybad = 0, mysig = 0;
    for (int i = threadIdx.x; i < 8192; i += 256) {
        unsigned short u = q16[i];
        int e = (u >> 7) & 0xFF;
        if (!(e == 0 || (e >= 100 && e <= 140))) mybad++;
    }
    for (int i = threadIdx.x; i < 2048; i += 256) {
        unsigned hi = q[2*i + 1];
        int e = (hi >> 20) & 0x7FF;
        if (e >= 1003 && e <= 1040) mysig++;
    }
    atomicAdd(&bad, mybad);
    atomicAdd(&sig, mysig);
    __syncthreads();
    if (threadIdx.x == 0)
        *dt = (bad < 400) ? 1 : ((sig > 1950) ? 2 : 0);
}

// ---------------------------------------------------------------------------
// FFT-384 (3 x radix-2 DIF FFT-128 + radix-3 DIT combine); fftshift pair
// folded as (-1)^n / (-1)^u; ortho 1/sqrt(384). In-place safe.
// MODE: 0 = plain, 1 = load-fused expand (rim*sens), 2 = store-fused dc.
// ---------------------------------------------------------------------------
#define NLINE 8
#define SP 385

template<int DIR, int AXIS, int MODE>
__global__ __launch_bounds__(256)
void fft384(const void* in, float2* out, const int* DTp, int srcExt,
            const void* aux1, const void* aux2,      // MODE1: rim,sens; MODE2: tgt,mask
            const int* FLAGp, const void* dcwp, float2* outk)
{
    __shared__ float2 tw[384];
    __shared__ float2 stage[NLINE * SP];
    __shared__ float2 work[4][384];
    const int tid = threadIdx.x;
    const int dt = (srcExt || MODE) ? *DTp : 0;
    for (int j = tid; j < 384; j += 256) {
        float s, c;
        sincosf(-6.283185307179586f * (float)j / 384.0f, &s, &c);
        tw[j] = make_float2(c, s);
    }
    const int img = blockIdx.x / 48;
    const int t0  = (blockIdx.x % 48) * NLINE;
    const size_t base = (size_t)img * NPIX;
    float2* dst = out + base;

    if (AXIS == 0) {
        if (MODE == 1) {
            const float2* rim = (const float2*)aux1;
            const size_t rbase = (size_t)(img >> 4) * NPIX;
            for (int f = tid; f < NLINE*384; f += 256) {
                int l = f / 384, n = f - l*384;
                size_t pix = (size_t)(t0 + l)*384 + n;
                stage[l*SP + n] = cmul(rim[rbase + pix], loadc2(aux2, dt, base + pix));
            }
        } else {
            for (int f = tid; f < NLINE*384; f += 256) {
                int l = f / 384, n = f - l*384;
                stage[l*SP + n] = loadc2(in, dt, base + (size_t)(t0 + l)*384 + n);
            }
        }
    } else {
        for (int f = tid; f < NLINE*384; f += 256) {
            int l = f & 7, n = f >> 3;
            stage[l*SP + n] = loadc2(in, dt, base + (size_t)n*384 + (t0 + l));
        }
    }
    __syncthreads();
    const int g    = tid >> 6;
    const int lane = tid & 63;
    float2* w = work[g];
    const float SCALE = 0.05103103630798288f;
    for (int it = 0; it < 2; ++it) {
        const int l = it*4 + g;
        #pragma unroll
        for (int m = 0; m < 6; ++m) {
            int n = lane + 64*m;
            float2 v = stage[l*SP + n];
            float sgn = (n & 1) ? -1.f : 1.f;
            int q = n / 3;
            int r3 = n - 3*q;
            w[r3*128 + q] = make_float2(v.x*sgn, v.y*sgn);
        }
        __syncthreads();
        #pragma unroll
        for (int s = 0; s < 7; ++s) {
            const int h = 64 >> s;
            const int tstep = 3 << s;
            const int j = lane & (h-1);
            const int i = ((lane & ~(h-1)) << 1) | j;
            float2 t = tw[j * tstep];
            if (DIR < 0) t.y = -t.y;
            #pragma unroll
            for (int n1 = 0; n1 < 3; ++n1) {
                float2* a = w + (n1 << 7);
                float2 u = a[i], v = a[i+h];
                float2 d = make_float2(u.x - v.x, u.y - v.y);
                a[i]   = make_float2(u.x + v.x, u.y + v.y);
                a[i+h] = cmul(d, t);
            }
            __syncthreads();
        }
        #pragma unroll
        for (int half = 0; half < 2; ++half) {
            int k2 = lane + 64*half;
            int r  = __brev((unsigned)k2) >> 25;
            float2 a0 = w[r], a1 = w[128 + r], a2 = w[256 + r];
            float2 t1 = tw[k2];
            float2 t2 = tw[(2*k2) % 384];
            float2 w3 = tw[128], w3b = tw[256];
            if (DIR < 0) { t1.y=-t1.y; t2.y=-t2.y; w3.y=-w3.y; w3b.y=-w3b.y; }
            float2 b1 = cmul(a1, t1), b2 = cmul(a2, t2);
            float2 X0 = make_float2(a0.x + b1.x + b2.x, a0.y + b1.y + b2.y);
            float2 c1 = cmul(w3, b1), c2 = cmul(w3b, b2);
            float2 X1 = make_float2(a0.x + c1.x + c2.x, a0.y + c1.y + c2.y);
            float2 d1 = cmul(w3b, b1), d2 = cmul(w3, b2);
            float2 X2 = make_float2(a0.x + d1.x + d2.x, a0.y + d1.y + d2.y);
            float sc = (k2 & 1) ? -SCALE : SCALE;
            stage[l*SP + k2      ] = make_float2(X0.x*sc, X0.y*sc);
            stage[l*SP + k2 + 128] = make_float2(X1.x*sc, X1.y*sc);
            stage[l*SP + k2 + 256] = make_float2(X2.x*sc, X2.y*sc);
        }
        __syncthreads();
    }
    if (AXIS == 0) {
        for (int f = tid; f < NLINE*384; f += 256) {
            int l = f / 384, n = f - l*384;
            dst[(size_t)(t0 + l)*384 + n] = stage[l*SP + n];
        }
    } else {
        if (MODE == 2) {
            const int fl = *FLAGp;
            const float dw = loads1(dcwp, dt, 0);
            const int bb = img >> 4;
            for (int f = tid; f < NLINE*384; f += 256) {
                int l = f & 7, n = f >> 3;
                int wcol = t0 + l;
                size_t pix = (size_t)n*384 + wcol;
                float2 v = stage[l*SP + n];
                int m;
                switch (fl) {
                    case 0:  m = ((const unsigned char*)aux2)[bb*384 + wcol] != 0; break;
                    case 4:  m = ((const unsigned short*)aux2)[bb*384 + wcol] != 0; break;
                    case 3:  m = ((const unsigned long long*)aux2)[bb*384 + wcol] != 0ULL; break;
                    default: m = ((const unsigned int*)aux2)[bb*384 + wcol] != 0u; break;
                }
                if (m) {
                    float2 r = loadc2(aux1, dt, base + pix);
                    v.x -= (v.x - r.x)*dw;
                    v.y -= (v.y - r.y)*dw;
                }
                dst[pix] = v;
                outk[base + pix] = v;      // FLOAT32 pred_kspace to d_out
            }
        } else {
            for (int f = tid; f < NLINE*384; f += 256) {
                int l = f & 7, n = f >> 3;
                dst[(size_t)n*384 + (t0 + l)] = stage[l*SP + n];
            }
        }
    }
}

// mask dtype classifier: 0=byte 2=32-bit 3=64-bit 4=16-bit (HW: FLAG=2 int32)
__global__ void detect_mask(const unsigned char* __restrict__ m, int* flag)
{
    __shared__ int sA, sB, sC, sD, sE;
    if (threadIdx.x == 0) { sA = sB = sC = sD = sE = 0; }
    __syncthreads();
    for (int i = threadIdx.x; i < 768; i += 256) {
        unsigned char v = m[i];
        if (v > 1) atomicOr(&sA, 1);
        if ((i & 3) && v) atomicOr(&sB, 1);
    }
    const unsigned short* m16 = (const unsigned short*)m;
    for (int i = threadIdx.x; i < 384; i += 256)
        if (!(i & 1) && m16[i]) atomicOr(&sC, 1);
    const unsigned int* m32 = (const unsigned int*)m;
    for (int i = threadIdx.x; i < 192; i += 256) {
        if ((i & 1) && m32[i]) atomicOr(&sD, 1);
        if (!(i & 1) && m32[i]) atomicOr(&sE, 1);
    }
    __syncthreads();
    if (threadIdx.x == 0) {
        int f;
        if (!sA) { if (sB) f = 0; else if (sD) f = 2; else f = 3; }
        else     { if (sC) f = 4; else if (sE) f = 2; else f = 3; }
        *flag = f;
    }
}

__global__ __launch_bounds__(256)
void reduce_sens(const float2* __restrict__ xin, const void* __restrict__ sens,
                 float2* __restrict__ ximg, const int* DTp)
{
    const int dt = *DTp;
    const int b = blockIdx.y;
    const int p = blockIdx.x*256 + threadIdx.x;
    float2 acc = make_float2(0.f, 0.f);
    for (int c = 0; c < CC; ++c) {
        size_t o = ((size_t)(b*CC + c))*NPIX + p;
        float2 a = xin[o];
        float2 s = loadc2(sens, dt, o);
        acc.x += a.x*s.x + a.y*s.y;     // x * conj(s)
        acc.y += a.y*s.x - a.x*s.y;
    }
    ximg[(size_t)b*NPIX + p] = acc;
}

__global__ __launch_bounds__(256)
void stats_kernel(const float2* __restrict__ ximg, float* __restrict__ ms)
{
    const int b = blockIdx.x;
    const int tid = threadIdx.x;
    float sx=0.f, sy=0.f, qx=0.f, qy=0.f;
    for (int p = tid; p < NPIX; p += 256) {
        float2 v = ximg[(size_t)b*NPIX + p];
        sx += v.x; sy += v.y; qx += v.x*v.x; qy += v.y*v.y;
    }
    __shared__ float r0[256], r1[256], r2[256], r3[256];
    r0[tid]=sx; r1[tid]=sy; r2[tid]=qx; r3[tid]=qy;
    __syncthreads();
    for (int s = 128; s > 0; s >>= 1) {
        if (tid < s) {
            r0[tid]+=r0[tid+s]; r1[tid]+=r1[tid+s];
            r2[tid]+=r2[tid+s]; r3[tid]+=r3[tid+s];
        }
        __syncthreads();
    }
    if (tid == 0) {
        const float N = (float)NPIX;
        float var0 = (r2[0] - r0[0]*r0[0]/N) / (N - 1.f);
        float var1 = (r3[0] - r1[0]*r1[0]/N) / (N - 1.f);
        ms[(b*2+0)*2]   = r0[0]/N;
        ms[(b*2+0)*2+1] = sqrtf(var0);
        ms[(b*2+1)*2]   = r1[0]/N;
        ms[(b*2+1)*2+1] = sqrtf(var1);
    }
}

// ---------------------------------------------------------------------------
// conv: wave-synchronous. 4 waves x 16 channels; per-wave hidden tile in LDS;
// no block barriers in the channel loop; final cross-wave reduction.
// ---------------------------------------------------------------------------
__global__ __launch_bounds__(256)
void conv_fused(const float2* __restrict__ ximg, const void* __restrict__ w1g,
                const void* __restrict__ b1g, const void* __restrict__ w2g,
                const void* __restrict__ b2g, const float* __restrict__ msg,
                float2* __restrict__ rim, const int* DTp)
{
    __shared__ float in0[20][21];
    __shared__ float in1[20][21];
    __shared__ float w1s[1152];
    __shared__ float w2s[1152];
    __shared__ float b1s[64];
    __shared__ float hidw[4][18*20];
    __shared__ float2 accs[4][256];

    const int dt = *DTp;
    const int b = blockIdx.z, bx = blockIdx.x, by = blockIdx.y;
    const int tid = threadIdx.x;
    const int wv = tid >> 6, lane = tid & 63;

    for (int f = tid; f < 1152; f += 256) {
        w1s[f] = loads1(w1g, dt, f);
        w2s[f] = loads1(w2g, dt, f);
    }
    if (tid < 64) b1s[tid] = loads1(b1g, dt, tid);
    const float mean0 = msg[(b*2+0)*2], istd0 = 1.f/msg[(b*2+0)*2+1];
    const float mean1 = msg[(b*2+1)*2], istd1 = 1.f/msg[(b*2+1)*2+1];
    for (int f = tid; f < 400; f += 256) {
        int yy = f / 20, xx = f - yy*20;
        int gy = by*16 + yy - 2, gx = bx*16 + xx - 2;
        float a = 0.f, c = 0.f;
        if (gy >= 0 && gy < HH && gx >= 0 && gx < WW) {
            float2 v = ximg[(size_t)b*NPIX + gy*WW + gx];
            a = (v.x - mean0)*istd0;
            c = (v.y - mean1)*istd1;
        }
        in0[yy][xx] = a; in1[yy][xx] = c;
    }
    __syncthreads();

    float a0[4] = {0.f,0.f,0.f,0.f}, a1[4] = {0.f,0.f,0.f,0.f};
    float* hid = hidw[wv];

    for (int j = 0; j < 16; ++j) {
        const int o = wv*16 + j;
        const float* wa = &w1s[o*18];
        const float bo = b1s[o];
        for (int idx = lane; idx < 324; idx += 64) {
            int yy = idx / 18, xx = idx - yy*18;
            int gy = by*16 + yy - 1, gx = bx*16 + xx - 1;
            float acc = bo;
            #pragma unroll
            for (int k = 0; k < 9; ++k) {
                acc += wa[k]   * in0[yy + k/3][xx + k%3];
                acc += wa[9+k] * in1[yy + k/3][xx + k%3];
            }
            hid[yy*20 + xx] = (gy >= 0 && gy < HH && gx >= 0 && gx < WW)
                            ? fmaxf(acc, 0.f) : 0.f;
        }
        __builtin_amdgcn_wave_barrier();   // wave-local LDS write->read ordering
        const float* w2a = &w2s[o*9];
        const float* w2b = &w2s[576 + o*9];
        #pragma unroll
        for (int q = 0; q < 4; ++q) {
            int p = lane + 64*q;
            int ty = p >> 4, tx = p & 15;
            #pragma unroll
            for (int k = 0; k < 9; ++k) {
                float h = hid[(ty + k/3)*20 + (tx + k%3)];
                a0[q] += w2a[k]*h;
                a1[q] += w2b[k]*h;
            }
        }
        __builtin_amdgcn_wave_barrier();   // before next channel overwrites hid
    }
    #pragma unroll
    for (int q = 0; q < 4; ++q)
        accs[wv][lane + 64*q] = make_float2(a0[q], a1[q]);
    __syncthreads();
    {
        const int p = tid;
        float s0 = loads1(b2g, dt, 0), s1 = loads1(b2g, dt, 1);
        #pragma unroll
        for (int wvi = 0; wvi < 4; ++wvi) {
            s0 += accs[wvi][p].x;
            s1 += accs[wvi][p].y;
        }
        const float std0 = msg[(b*2+0)*2+1], std1 = msg[(b*2+1)*2+1];
        int ty = p >> 4, tx = p & 15;
        rim[(size_t)b*NPIX + (by*16+ty)*WW + (bx*16+tx)]
            = make_float2(s0*std0 + mean0, s1*std1 + mean1);
    }
}

__global__ __launch_bounds__(384)
void predictor(const float2* __restrict__ kimg, const void* __restrict__ wmp,
               const void* __restrict__ bmp, float* __restrict__ prob,
               float* __restrict__ outp, const int* DTp)
{
    const int dt = *DTp;
    const int b = blockIdx.x, w = threadIdx.x;
    float s0 = 0.f, s1 = 0.f;
    for (int h = 0; h < HH; ++h) {
        float2 v = kimg[((size_t)b*HH + h)*WW + w];
        s0 += v.x; s1 += v.y;
    }
    float logit = (s0*loads1(wmp,dt,0) + s1*loads1(wmp,dt,1)) * (1.0f/384.0f)
                + loads1(bmp,dt,0);
    __shared__ float red[8];
    float m = logit;
    for (int o = 32; o > 0; o >>= 1) m = fmaxf(m, __shfl_down(m, o, 64));
    int wid = w >> 6, lane = w & 63;
    if (lane == 0) red[wid] = m;
    __syncthreads();
    if (w == 0) { float mm = red[0]; for (int i = 1; i < 6; ++i) mm = fmaxf(mm, red[i]); red[6] = mm; }
    __syncthreads();
    m = red[6];
    float e = expf(logit - m);
    float s = e;
    for (int o = 32; o > 0; o >>= 1) s += __shfl_down(s, o, 64);
    __syncthreads();
    if (lane == 0) red[wid] = s;
    __syncthreads();
    if (w == 0) { float ss = 0.f; for (int i = 0; i < 6; ++i) ss += red[i]; red[7] = ss; }
    __syncthreads();
    float pr = e / red[7];
    prob[b*WW + w] = pr;
    outp[b*WW + w] = pr;
}

__global__ __launch_bounds__(384)
void update_mask_k(const float* __restrict__ prob, const void* __restrict__ cmask,
                   const void* __restrict__ add_list, const void* __restrict__ itp,
                   float* __restrict__ outm, const int* DTp)
{
    const int dt = *DTp;
    const int b = blockIdx.x, w = threadIdx.x;
    __shared__ float p[384];
    float cm = loads1(cmask, dt, b*WW + w);
    float pv = prob[b*WW + w] * (1.0f - cm);
    p[w] = pv;
    __syncthreads();
    int rank = 0;
    for (int i = 0; i < 384; ++i) {
        float q = p[i];
        rank += (q > pv) || (q == pv && i < w);
    }
    int it = flex_int1(itp);
    if (it < 0 || it > 7) it = 0;
    int addn = flex_int_arr(add_list, b*8 + it);
    float val = cm + ((rank < addn) ? 1.0f : 0.0f);
    outm[b*WW + w] = val;
}

// ---------------------------------------------------------------------------
extern "C" void kernel_launch(void* const* d_in, const int* in_sizes, int n_in,
                              void* d_out, int out_size, void* d_ws, size_t ws_size,
                              hipStream_t stream)
{
    const void* src  = d_in[0];   // current_kspace
    const void* tgt  = d_in[1];   // ref_kspace
    const void* mask = d_in[2];
    const void* sens = d_in[3];
    const void* itp  = d_in[4];
    const void* cmask= d_in[5];
    const void* addl = d_in[7];
    const void* dcw  = d_in[8];
    const void* w1   = d_in[9];
    const void* b1   = d_in[10];
    const void* w2   = d_in[11];
    const void* b2   = d_in[12];
    const void* wmp  = d_in[13];
    const void* bmp  = d_in[14];
    float* out = (float*)d_out;   // FLOAT32 output buffer

    float* ws = (float*)d_ws;
    const size_t OFF_XIMG = 9437184;
    const size_t OFF_RIM  = OFF_XIMG + 589824;
    const size_t OFF_MS   = OFF_RIM  + 589824;
    const size_t OFF_PROB = OFF_MS + 8;
    const size_t OFF_FLAG = OFF_PROB + 768;
    const size_t OFF_DT   = OFF_FLAG + 4;

    float2* A    = (float2*)ws;
    float2* XIMG = (float2*)(ws + OFF_XIMG);
    float2* RIM  = (float2*)(ws + OFF_RIM);
    float*  MS   = ws + OFF_MS;
    float*  PROB = ws + OFF_PROB;
    int*    FLAG = (int*)(ws + OFF_FLAG);
    int*    DT   = (int*)(ws + OFF_DT);

    const int gBig   = (BB*CC)*48;
    const int gSmall = BB*48;

    detect_dtype<<<1, 256, 0, stream>>>((const unsigned*)src, DT);
    detect_mask<<<1, 256, 0, stream>>>((const unsigned char*)mask, FLAG);

    // sens_reduce(current_kspace): ifft2c then sum x*conj(s)
    fft384<-1,0,0><<<gBig, 256, 0, stream>>>(src, A, DT, 1, nullptr, nullptr, nullptr, nullptr, nullptr);
    fft384<-1,1,0><<<gBig, 256, 0, stream>>>(A, A, DT, 0, nullptr, nullptr, nullptr, nullptr, nullptr);
    reduce_sens<<<dim3((NPIX/256), BB), 256, 0, stream>>>(A, sens, XIMG, DT);
    stats_kernel<<<BB, 256, 0, stream>>>(XIMG, MS);

    // apply_model (wave-synchronous conv)
    conv_fused<<<dim3(24,24,BB), 256, 0, stream>>>(XIMG, w1, b1, w2, b2, MS, RIM, DT);

    // sens_expand fused into fft2c row pass (load = rim*sens)
    fft384<1,0,1><<<gBig, 256, 0, stream>>>(nullptr, A, DT, 0, RIM, sens, nullptr, nullptr, nullptr);
    // fft2c col pass with dc fused into store (A := pred, d_out := pred f32)
    fft384<1,1,2><<<gBig, 256, 0, stream>>>(A, A, DT, 0, tgt, mask, FLAG, dcw, (float2*)out);

    // sens_reduce(pred_kspace)
    fft384<-1,0,0><<<gBig, 256, 0, stream>>>(A, A, DT, 0, nullptr, nullptr, nullptr, nullptr, nullptr);
    fft384<-1,1,0><<<gBig, 256, 0, stream>>>(A, A, DT, 0, nullptr, nullptr, nullptr, nullptr, nullptr);
    reduce_sens<<<dim3((NPIX/256), BB), 256, 0, stream>>>(A, sens, XIMG, DT);

    // kim = fft2c(restore_im_dc[:,0])
    fft384<1,0,0><<<gSmall, 256, 0, stream>>>(XIMG, XIMG, DT, 0, nullptr, nullptr, nullptr, nullptr, nullptr);
    fft384<1,1,0><<<gSmall, 256, 0, stream>>>(XIMG, XIMG, DT, 0, nullptr, nullptr, nullptr, nullptr, nullptr);

    // mask predictor + mask update (FLOAT32 outputs)
    predictor<<<BB, 384, 0, stream>>>(XIMG, wmp, bmp, PROB, out + 9437184 + 768, DT);
    update_mask_k<<<BB, 384, 0, stream>>>(PROB, cmask, addl, itp, out + 9437184, DT);
}

// Round 21
// 418.366 us; speedup vs baseline: 1.5004x; 1.3460x over previous
//
#include <hip/hip_runtime.h>
#include <hip/hip_bf16.h>
#include <math.h>

#define HH 384
#define WW 384
#define NPIX (HH*WW)        // 147456
#define BB 2
#define CC 16
#define NKF 9437184         // pred_kspace float count

__device__ inline float2 cmul(float2 a, float2 b) {
    return make_float2(a.x*b.x - a.y*b.y, a.x*b.y + a.y*b.x);
}
__device__ inline float bf2f(unsigned short u) {
    union { unsigned int i; float f; } c; c.i = ((unsigned)u) << 16; return c.f;
}
__device__ inline float2 loadc2(const void* p, int dt, size_t i) {
    if (dt == 1) { ushort2 u = ((const ushort2*)p)[i];
        return make_float2(bf2f(u.x), bf2f(u.y)); }
    if (dt == 2) { double2 d = ((const double2*)p)[i];
        return make_float2((float)d.x, (float)d.y); }
    return ((const float2*)p)[i];
}
__device__ inline float loads1(const void* p, int dt, size_t i) {
    if (dt == 1) return bf2f(((const unsigned short*)p)[i]);
    if (dt == 2) return (float)((const double*)p)[i];
    return ((const float*)p)[i];
}
__device__ inline int flex_int1(const void* p) {
    unsigned v = ((const unsigned*)p)[0];
    if (v < 1000000u) return (int)v;
    float f = ((const float*)p)[0];
    if (f > -1e6f && f < 1e6f && f == floorf(f)) return (int)f;
    return (int)((const double*)p)[0];
}
__device__ inline int flex_int_arr(const void* p, int i) {
    const unsigned* u = (const unsigned*)p;
    if (u[1] == 0u && u[3] == 0u) return (int)u[2*i];   // int64
    if (u[0] >= 1u && u[0] < 1000000u) return (int)u[i];// int32
    float f = ((const float*)p)[i];
    if (f > -1e6f && f < 1e6f) return (int)f;
    return (int)((const double*)p)[i];
}

__global__ void detect_dtype(const unsigned* __restrict__ q, int* dt)
{
    __shared__ int bad, sig;
    if (threadIdx.x == 0) { bad = 0; sig = 0; }
    __syncthreads();
    const unsigned short* q16 = (const unsigned short*)q;
    int mybad = 0, mysig = 0;
    for (int i = threadIdx.x; i < 8192; i += 256) {
        unsigned short u = q16[i];
        int e = (u >> 7) & 0xFF;
        if (!(e == 0 || (e >= 100 && e <= 140))) mybad++;
    }
    for (int i = threadIdx.x; i < 2048; i += 256) {
        unsigned hi = q[2*i + 1];
        int e = (hi >> 20) & 0x7FF;
        if (e >= 1003 && e <= 1040) mysig++;
    }
    atomicAdd(&bad, mybad);
    atomicAdd(&sig, mysig);
    __syncthreads();
    if (threadIdx.x == 0)
        *dt = (bad < 400) ? 1 : ((sig > 1950) ? 2 : 0);
}

// ---------------------------------------------------------------------------
// FFT-384; fftshift folded; ortho. MODE: 0 plain, 1 load-fused expand,
// 2 store-fused dc.
// ---------------------------------------------------------------------------
#define NLINE 8
#define SP 385

template<int DIR, int AXIS, int MODE>
__global__ __launch_bounds__(256)
void fft384(const void* in, float2* out, const int* DTp, int srcExt,
            const void* aux1, const void* aux2,
            const int* FLAGp, const void* dcwp, float2* outk)
{
    __shared__ float2 tw[384];
    __shared__ float2 stage[NLINE * SP];
    __shared__ float2 work[4][384];
    const int tid = threadIdx.x;
    const int dt = (srcExt || MODE) ? *DTp : 0;
    for (int j = tid; j < 384; j += 256) {
        float s, c;
        sincosf(-6.283185307179586f * (float)j / 384.0f, &s, &c);
        tw[j] = make_float2(c, s);
    }
    const int img = blockIdx.x / 48;
    const int t0  = (blockIdx.x % 48) * NLINE;
    const size_t base = (size_t)img * NPIX;
    float2* dst = out + base;

    if (AXIS == 0) {
        if (MODE == 1) {
            const float2* rim = (const float2*)aux1;
            const size_t rbase = (size_t)(img >> 4) * NPIX;
            for (int f = tid; f < NLINE*384; f += 256) {
                int l = f / 384, n = f - l*384;
                size_t pix = (size_t)(t0 + l)*384 + n;
                stage[l*SP + n] = cmul(rim[rbase + pix], loadc2(aux2, dt, base + pix));
            }
        } else {
            for (int f = tid; f < NLINE*384; f += 256) {
                int l = f / 384, n = f - l*384;
                stage[l*SP + n] = loadc2(in, dt, base + (size_t)(t0 + l)*384 + n);
            }
        }
    } else {
        for (int f = tid; f < NLINE*384; f += 256) {
            int l = f & 7, n = f >> 3;
            stage[l*SP + n] = loadc2(in, dt, base + (size_t)n*384 + (t0 + l));
        }
    }
    __syncthreads();
    const int g    = tid >> 6;
    const int lane = tid & 63;
    float2* w = work[g];
    const float SCALE = 0.05103103630798288f;
    for (int it = 0; it < 2; ++it) {
        const int l = it*4 + g;
        #pragma unroll
        for (int m = 0; m < 6; ++m) {
            int n = lane + 64*m;
            float2 v = stage[l*SP + n];
            float sgn = (n & 1) ? -1.f : 1.f;
            int q = n / 3;
            int r3 = n - 3*q;
            w[r3*128 + q] = make_float2(v.x*sgn, v.y*sgn);
        }
        __syncthreads();
        #pragma unroll
        for (int s = 0; s < 7; ++s) {
            const int h = 64 >> s;
            const int tstep = 3 << s;
            const int j = lane & (h-1);
            const int i = ((lane & ~(h-1)) << 1) | j;
            float2 t = tw[j * tstep];
            if (DIR < 0) t.y = -t.y;
            #pragma unroll
            for (int n1 = 0; n1 < 3; ++n1) {
                float2* a = w + (n1 << 7);
                float2 u = a[i], v = a[i+h];
                float2 d = make_float2(u.x - v.x, u.y - v.y);
                a[i]   = make_float2(u.x + v.x, u.y + v.y);
                a[i+h] = cmul(d, t);
            }
            __syncthreads();
        }
        #pragma unroll
        for (int half = 0; half < 2; ++half) {
            int k2 = lane + 64*half;
            int r  = __brev((unsigned)k2) >> 25;
            float2 a0 = w[r], a1 = w[128 + r], a2 = w[256 + r];
            float2 t1 = tw[k2];
            float2 t2 = tw[(2*k2) % 384];
            float2 w3 = tw[128], w3b = tw[256];
            if (DIR < 0) { t1.y=-t1.y; t2.y=-t2.y; w3.y=-w3.y; w3b.y=-w3b.y; }
            float2 b1 = cmul(a1, t1), b2 = cmul(a2, t2);
            float2 X0 = make_float2(a0.x + b1.x + b2.x, a0.y + b1.y + b2.y);
            float2 c1 = cmul(w3, b1), c2 = cmul(w3b, b2);
            float2 X1 = make_float2(a0.x + c1.x + c2.x, a0.y + c1.y + c2.y);
            float2 d1 = cmul(w3b, b1), d2 = cmul(w3, b2);
            float2 X2 = make_float2(a0.x + d1.x + d2.x, a0.y + d1.y + d2.y);
            float sc = (k2 & 1) ? -SCALE : SCALE;
            stage[l*SP + k2      ] = make_float2(X0.x*sc, X0.y*sc);
            stage[l*SP + k2 + 128] = make_float2(X1.x*sc, X1.y*sc);
            stage[l*SP + k2 + 256] = make_float2(X2.x*sc, X2.y*sc);
        }
        __syncthreads();
    }
    if (AXIS == 0) {
        for (int f = tid; f < NLINE*384; f += 256) {
            int l = f / 384, n = f - l*384;
            dst[(size_t)(t0 + l)*384 + n] = stage[l*SP + n];
        }
    } else {
        if (MODE == 2) {
            const int fl = *FLAGp;
            const float dw = loads1(dcwp, dt, 0);
            const int bb = img >> 4;
            for (int f = tid; f < NLINE*384; f += 256) {
                int l = f & 7, n = f >> 3;
                int wcol = t0 + l;
                size_t pix = (size_t)n*384 + wcol;
                float2 v = stage[l*SP + n];
                int m;
                switch (fl) {
                    case 0:  m = ((const unsigned char*)aux2)[bb*384 + wcol] != 0; break;
                    case 4:  m = ((const unsigned short*)aux2)[bb*384 + wcol] != 0; break;
                    case 3:  m = ((const unsigned long long*)aux2)[bb*384 + wcol] != 0ULL; break;
                    default: m = ((const unsigned int*)aux2)[bb*384 + wcol] != 0u; break;
                }
                if (m) {
                    float2 r = loadc2(aux1, dt, base + pix);
                    v.x -= (v.x - r.x)*dw;
                    v.y -= (v.y - r.y)*dw;
                }
                dst[pix] = v;
                outk[base + pix] = v;
            }
        } else {
            for (int f = tid; f < NLINE*384; f += 256) {
                int l = f & 7, n = f >> 3;
                dst[(size_t)n*384 + (t0 + l)] = stage[l*SP + n];
            }
        }
    }
}

__global__ void detect_mask(const unsigned char* __restrict__ m, int* flag)
{
    __shared__ int sA, sB, sC, sD, sE;
    if (threadIdx.x == 0) { sA = sB = sC = sD = sE = 0; }
    __syncthreads();
    for (int i = threadIdx.x; i < 768; i += 256) {
        unsigned char v = m[i];
        if (v > 1) atomicOr(&sA, 1);
        if ((i & 3) && v) atomicOr(&sB, 1);
    }
    const unsigned short* m16 = (const unsigned short*)m;
    for (int i = threadIdx.x; i < 384; i += 256)
        if (!(i & 1) && m16[i]) atomicOr(&sC, 1);
    const unsigned int* m32 = (const unsigned int*)m;
    for (int i = threadIdx.x; i < 192; i += 256) {
        if ((i & 1) && m32[i]) atomicOr(&sD, 1);
        if (!(i & 1) && m32[i]) atomicOr(&sE, 1);
    }
    __syncthreads();
    if (threadIdx.x == 0) {
        int f;
        if (!sA) { if (sB) f = 0; else if (sD) f = 2; else f = 3; }
        else     { if (sC) f = 4; else if (sE) f = 2; else f = 3; }
        *flag = f;
    }
}

// reduce_sens with optional fused stats partials (per-block wave reduction)
template<bool WITH_STATS>
__global__ __launch_bounds__(256)
void reduce_sens(const float2* __restrict__ xin, const void* __restrict__ sens,
                 float2* __restrict__ ximg, const int* DTp,
                 float* __restrict__ partials)   // [b][576][4]
{
    const int dt = *DTp;
    const int b = blockIdx.y;
    const int p = blockIdx.x*256 + threadIdx.x;
    float2 acc = make_float2(0.f, 0.f);
    for (int c = 0; c < CC; ++c) {
        size_t o = ((size_t)(b*CC + c))*NPIX + p;
        float2 a = xin[o];
        float2 s = loadc2(sens, dt, o);
        acc.x += a.x*s.x + a.y*s.y;     // x * conj(s)
        acc.y += a.y*s.x - a.x*s.y;
    }
    ximg[(size_t)b*NPIX + p] = acc;
    if (WITH_STATS) {
        float sx = acc.x, sy = acc.y, qx = acc.x*acc.x, qy = acc.y*acc.y;
        #pragma unroll
        for (int o = 32; o > 0; o >>= 1) {
            sx += __shfl_down(sx, o, 64); sy += __shfl_down(sy, o, 64);
            qx += __shfl_down(qx, o, 64); qy += __shfl_down(qy, o, 64);
        }
        __shared__ float red[4][4];
        const int wv = threadIdx.x >> 6, lane = threadIdx.x & 63;
        if (lane == 0) {
            red[wv][0] = sx; red[wv][1] = sy; red[wv][2] = qx; red[wv][3] = qy;
        }
        __syncthreads();
        if (threadIdx.x == 0) {
            float t0 = red[0][0]+red[1][0]+red[2][0]+red[3][0];
            float t1 = red[0][1]+red[1][1]+red[2][1]+red[3][1];
            float t2 = red[0][2]+red[1][2]+red[2][2]+red[3][2];
            float t3 = red[0][3]+red[1][3]+red[2][3]+red[3][3];
            float* dst = partials + ((size_t)b*576 + blockIdx.x)*4;
            dst[0] = t0; dst[1] = t1; dst[2] = t2; dst[3] = t3;
        }
    }
}

// 576 partials -> mean/std per (b, channel); 1 block per b, deterministic
__global__ __launch_bounds__(256)
void stats_finalize(const float* __restrict__ partials, float* __restrict__ ms)
{
    const int b = blockIdx.x;
    const int tid = threadIdx.x;
    float sx=0.f, sy=0.f, qx=0.f, qy=0.f;
    for (int i = tid; i < 576; i += 256) {
        const float* p = partials + ((size_t)b*576 + i)*4;
        sx += p[0]; sy += p[1]; qx += p[2]; qy += p[3];
    }
    __shared__ float r0[256], r1[256], r2[256], r3[256];
    r0[tid]=sx; r1[tid]=sy; r2[tid]=qx; r3[tid]=qy;
    __syncthreads();
    for (int s = 128; s > 0; s >>= 1) {
        if (tid < s) {
            r0[tid]+=r0[tid+s]; r1[tid]+=r1[tid+s];
            r2[tid]+=r2[tid+s]; r3[tid]+=r3[tid+s];
        }
        __syncthreads();
    }
    if (tid == 0) {
        const float N = (float)NPIX;
        float var0 = (r2[0] - r0[0]*r0[0]/N) / (N - 1.f);
        float var1 = (r3[0] - r1[0]*r1[0]/N) / (N - 1.f);
        ms[(b*2+0)*2]   = r0[0]/N;
        ms[(b*2+0)*2+1] = sqrtf(var0);
        ms[(b*2+1)*2]   = r1[0]/N;
        ms[(b*2+1)*2+1] = sqrtf(var1);
    }
}

// conv: wave-synchronous (round-20 design, verified)
__global__ __launch_bounds__(256)
void conv_fused(const float2* __restrict__ ximg, const void* __restrict__ w1g,
                const void* __restrict__ b1g, const void* __restrict__ w2g,
                const void* __restrict__ b2g, const float* __restrict__ msg,
                float2* __restrict__ rim, const int* DTp)
{
    __shared__ float in0[20][21];
    __shared__ float in1[20][21];
    __shared__ float w1s[1152];
    __shared__ float w2s[1152];
    __shared__ float b1s[64];
    __shared__ float hidw[4][18*20];
    __shared__ float2 accs[4][256];

    const int dt = *DTp;
    const int b = blockIdx.z, bx = blockIdx.x, by = blockIdx.y;
    const int tid = threadIdx.x;
    const int wv = tid >> 6, lane = tid & 63;

    for (int f = tid; f < 1152; f += 256) {
        w1s[f] = loads1(w1g, dt, f);
        w2s[f] = loads1(w2g, dt, f);
    }
    if (tid < 64) b1s[tid] = loads1(b1g, dt, tid);
    const float mean0 = msg[(b*2+0)*2], istd0 = 1.f/msg[(b*2+0)*2+1];
    const float mean1 = msg[(b*2+1)*2], istd1 = 1.f/msg[(b*2+1)*2+1];
    for (int f = tid; f < 400; f += 256) {
        int yy = f / 20, xx = f - yy*20;
        int gy = by*16 + yy - 2, gx = bx*16 + xx - 2;
        float a = 0.f, c = 0.f;
        if (gy >= 0 && gy < HH && gx >= 0 && gx < WW) {
            float2 v = ximg[(size_t)b*NPIX + gy*WW + gx];
            a = (v.x - mean0)*istd0;
            c = (v.y - mean1)*istd1;
        }
        in0[yy][xx] = a; in1[yy][xx] = c;
    }
    __syncthreads();

    float a0[4] = {0.f,0.f,0.f,0.f}, a1[4] = {0.f,0.f,0.f,0.f};
    float* hid = hidw[wv];

    for (int j = 0; j < 16; ++j) {
        const int o = wv*16 + j;
        const float* wa = &w1s[o*18];
        const float bo = b1s[o];
        for (int idx = lane; idx < 324; idx += 64) {
            int yy = idx / 18, xx = idx - yy*18;
            int gy = by*16 + yy - 1, gx = bx*16 + xx - 1;
            float acc = bo;
            #pragma unroll
            for (int k = 0; k < 9; ++k) {
                acc += wa[k]   * in0[yy + k/3][xx + k%3];
                acc += wa[9+k] * in1[yy + k/3][xx + k%3];
            }
            hid[yy*20 + xx] = (gy >= 0 && gy < HH && gx >= 0 && gx < WW)
                            ? fmaxf(acc, 0.f) : 0.f;
        }
        __builtin_amdgcn_wave_barrier();
        const float* w2a = &w2s[o*9];
        const float* w2b = &w2s[576 + o*9];
        #pragma unroll
        for (int q = 0; q < 4; ++q) {
            int p = lane + 64*q;
            int ty = p >> 4, tx = p & 15;
            #pragma unroll
            for (int k = 0; k < 9; ++k) {
                float h = hid[(ty + k/3)*20 + (tx + k%3)];
                a0[q] += w2a[k]*h;
                a1[q] += w2b[k]*h;
            }
        }
        __builtin_amdgcn_wave_barrier();
    }
    #pragma unroll
    for (int q = 0; q < 4; ++q)
        accs[wv][lane + 64*q] = make_float2(a0[q], a1[q]);
    __syncthreads();
    {
        const int p = tid;
        float s0 = loads1(b2g, dt, 0), s1 = loads1(b2g, dt, 1);
        #pragma unroll
        for (int wvi = 0; wvi < 4; ++wvi) {
            s0 += accs[wvi][p].x;
            s1 += accs[wvi][p].y;
        }
        const float std0 = msg[(b*2+0)*2+1], std1 = msg[(b*2+1)*2+1];
        int ty = p >> 4, tx = p & 15;
        rim[(size_t)b*NPIX + (by*16+ty)*WW + (bx*16+tx)]
            = make_float2(s0*std0 + mean0, s1*std1 + mean1);
    }
}

__global__ __launch_bounds__(384)
void predictor(const float2* __restrict__ kimg, const void* __restrict__ wmp,
               const void* __restrict__ bmp, float* __restrict__ prob,
               float* __restrict__ outp, const int* DTp)
{
    const int dt = *DTp;
    const int b = blockIdx.x, w = threadIdx.x;
    float s0 = 0.f, s1 = 0.f;
    for (int h = 0; h < HH; ++h) {
        float2 v = kimg[((size_t)b*HH + h)*WW + w];
        s0 += v.x; s1 += v.y;
    }
    float logit = (s0*loads1(wmp,dt,0) + s1*loads1(wmp,dt,1)) * (1.0f/384.0f)
                + loads1(bmp,dt,0);
    __shared__ float red[8];
    float m = logit;
    for (int o = 32; o > 0; o >>= 1) m = fmaxf(m, __shfl_down(m, o, 64));
    int wid = w >> 6, lane = w & 63;
    if (lane == 0) red[wid] = m;
    __syncthreads();
    if (w == 0) { float mm = red[0]; for (int i = 1; i < 6; ++i) mm = fmaxf(mm, red[i]); red[6] = mm; }
    __syncthreads();
    m = red[6];
    float e = expf(logit - m);
    float s = e;
    for (int o = 32; o > 0; o >>= 1) s += __shfl_down(s, o, 64);
    __syncthreads();
    if (lane == 0) red[wid] = s;
    __syncthreads();
    if (w == 0) { float ss = 0.f; for (int i = 0; i < 6; ++i) ss += red[i]; red[7] = ss; }
    __syncthreads();
    float pr = e / red[7];
    prob[b*WW + w] = pr;
    outp[b*WW + w] = pr;
}

__global__ __launch_bounds__(384)
void update_mask_k(const float* __restrict__ prob, const void* __restrict__ cmask,
                   const void* __restrict__ add_list, const void* __restrict__ itp,
                   float* __restrict__ outm, const int* DTp)
{
    const int dt = *DTp;
    const int b = blockIdx.x, w = threadIdx.x;
    __shared__ float p[384];
    float cm = loads1(cmask, dt, b*WW + w);
    float pv = prob[b*WW + w] * (1.0f - cm);
    p[w] = pv;
    __syncthreads();
    int rank = 0;
    for (int i = 0; i < 384; ++i) {
        float q = p[i];
        rank += (q > pv) || (q == pv && i < w);
    }
    int it = flex_int1(itp);
    if (it < 0 || it > 7) it = 0;
    int addn = flex_int_arr(add_list, b*8 + it);
    float val = cm + ((rank < addn) ? 1.0f : 0.0f);
    outm[b*WW + w] = val;
}

// ---------------------------------------------------------------------------
extern "C" void kernel_launch(void* const* d_in, const int* in_sizes, int n_in,
                              void* d_out, int out_size, void* d_ws, size_t ws_size,
                              hipStream_t stream)
{
    const void* src  = d_in[0];
    const void* tgt  = d_in[1];
    const void* mask = d_in[2];
    const void* sens = d_in[3];
    const void* itp  = d_in[4];
    const void* cmask= d_in[5];
    const void* addl = d_in[7];
    const void* dcw  = d_in[8];
    const void* w1   = d_in[9];
    const void* b1   = d_in[10];
    const void* w2   = d_in[11];
    const void* b2   = d_in[12];
    const void* wmp  = d_in[13];
    const void* bmp  = d_in[14];
    float* out = (float*)d_out;

    float* ws = (float*)d_ws;
    const size_t OFF_XIMG = 9437184;
    const size_t OFF_RIM  = OFF_XIMG + 589824;
    const size_t OFF_MS   = OFF_RIM  + 589824;
    const size_t OFF_PROB = OFF_MS + 8;
    const size_t OFF_FLAG = OFF_PROB + 768;
    const size_t OFF_DT   = OFF_FLAG + 4;
    const size_t OFF_PART = OFF_DT + 4;     // 2*576*4 floats

    float2* A    = (float2*)ws;
    float2* XIMG = (float2*)(ws + OFF_XIMG);
    float2* RIM  = (float2*)(ws + OFF_RIM);
    float*  MS   = ws + OFF_MS;
    float*  PROB = ws + OFF_PROB;
    int*    FLAG = (int*)(ws + OFF_FLAG);
    int*    DT   = (int*)(ws + OFF_DT);
    float*  PART = ws + OFF_PART;

    const int gBig   = (BB*CC)*48;
    const int gSmall = BB*48;

    detect_dtype<<<1, 256, 0, stream>>>((const unsigned*)src, DT);
    detect_mask<<<1, 256, 0, stream>>>((const unsigned char*)mask, FLAG);

    // sens_reduce(current_kspace) + fused stats partials
    fft384<-1,0,0><<<gBig, 256, 0, stream>>>(src, A, DT, 1, nullptr, nullptr, nullptr, nullptr, nullptr);
    fft384<-1,1,0><<<gBig, 256, 0, stream>>>(A, A, DT, 0, nullptr, nullptr, nullptr, nullptr, nullptr);
    reduce_sens<true><<<dim3((NPIX/256), BB), 256, 0, stream>>>(A, sens, XIMG, DT, PART);
    stats_finalize<<<BB, 256, 0, stream>>>(PART, MS);

    // apply_model
    conv_fused<<<dim3(24,24,BB), 256, 0, stream>>>(XIMG, w1, b1, w2, b2, MS, RIM, DT);

    // sens_expand fused into fft2c row pass; dc fused into col-pass store
    fft384<1,0,1><<<gBig, 256, 0, stream>>>(nullptr, A, DT, 0, RIM, sens, nullptr, nullptr, nullptr);
    fft384<1,1,2><<<gBig, 256, 0, stream>>>(A, A, DT, 0, tgt, mask, FLAG, dcw, (float2*)out);

    // sens_reduce(pred_kspace) — no stats
    fft384<-1,0,0><<<gBig, 256, 0, stream>>>(A, A, DT, 0, nullptr, nullptr, nullptr, nullptr, nullptr);
    fft384<-1,1,0><<<gBig, 256, 0, stream>>>(A, A, DT, 0, nullptr, nullptr, nullptr, nullptr, nullptr);
    reduce_sens<false><<<dim3((NPIX/256), BB), 256, 0, stream>>>(A, sens, XIMG, DT, nullptr);

    // kim = fft2c(restore_im_dc[:,0])
    fft384<1,0,0><<<gSmall, 256, 0, stream>>>(XIMG, XIMG, DT, 0, nullptr, nullptr, nullptr, nullptr, nullptr);
    fft384<1,1,0><<<gSmall, 256, 0, stream>>>(XIMG, XIMG, DT, 0, nullptr, nullptr, nullptr, nullptr, nullptr);

    // predictor + mask update (FLOAT32 outputs)
    predictor<<<BB, 384, 0, stream>>>(XIMG, wmp, bmp, PROB, out + 9437184 + 768, DT);
    update_mask_k<<<BB, 384, 0, stream>>>(PROB, cmask, addl, itp, out + 9437184, DT);
}

// Round 22
// 393.703 us; speedup vs baseline: 1.5944x; 1.0626x over previous
//
#include <hip/hip_runtime.h>
#include <hip/hip_bf16.h>
#include <math.h>

#define HH 384
#define WW 384
#define NPIX (HH*WW)        // 147456
#define BB 2
#define CC 16
#define NKF 9437184         // pred_kspace float count

__device__ inline float2 cmul(float2 a, float2 b) {
    return make_float2(a.x*b.x - a.y*b.y, a.x*b.y + a.y*b.x);
}
__device__ inline float bf2f(unsigned short u) {
    union { unsigned int i; float f; } c; c.i = ((unsigned)u) << 16; return c.f;
}
__device__ inline float2 loadc2(const void* p, int dt, size_t i) {
    if (dt == 1) { ushort2 u = ((const ushort2*)p)[i];
        return make_float2(bf2f(u.x), bf2f(u.y)); }
    if (dt == 2) { double2 d = ((const double2*)p)[i];
        return make_float2((float)d.x, (float)d.y); }
    return ((const float2*)p)[i];
}
__device__ inline float loads1(const void* p, int dt, size_t i) {
    if (dt == 1) return bf2f(((const unsigned short*)p)[i]);
    if (dt == 2) return (float)((const double*)p)[i];
    return ((const float*)p)[i];
}
__device__ inline int flex_int1(const void* p) {
    unsigned v = ((const unsigned*)p)[0];
    if (v < 1000000u) return (int)v;
    float f = ((const float*)p)[0];
    if (f > -1e6f && f < 1e6f && f == floorf(f)) return (int)f;
    return (int)((const double*)p)[0];
}
__device__ inline int flex_int_arr(const void* p, int i) {
    const unsigned* u = (const unsigned*)p;
    if (u[1] == 0u && u[3] == 0u) return (int)u[2*i];   // int64
    if (u[0] >= 1u && u[0] < 1000000u) return (int)u[i];// int32
    float f = ((const float*)p)[i];
    if (f > -1e6f && f < 1e6f) return (int)f;
    return (int)((const double*)p)[i];
}

__global__ void detect_dtype(const unsigned* __restrict__ q, int* dt)
{
    __shared__ int bad, sig;
    if (threadIdx.x == 0) { bad = 0; sig = 0; }
    __syncthreads();
    const unsigned short* q16 = (const unsigned short*)q;
    int mybad = 0, mysig = 0;
    for (int i = threadIdx.x; i < 8192; i += 256) {
        unsigned short u = q16[i];
        int e = (u >> 7) & 0xFF;
        if (!(e == 0 || (e >= 100 && e <= 140))) mybad++;
    }
    for (int i = threadIdx.x; i < 2048; i += 256) {
        unsigned hi = q[2*i + 1];
        int e = (hi >> 20) & 0x7FF;
        if (e >= 1003 && e <= 1040) mysig++;
    }
    atomicAdd(&bad, mybad);
    atomicAdd(&sig, mysig);
    __syncthreads();
    if (threadIdx.x == 0)
        *dt = (bad < 400) ? 1 : ((sig > 1950) ? 2 : 0);
}

// ---------------------------------------------------------------------------
// FFT-384; fftshift folded; ortho. MODE: 0 plain, 1 load-fused expand,
// 2 store-fused dc.
// ---------------------------------------------------------------------------
#define NLINE 8
#define SP 385

template<int DIR, int AXIS, int MODE>
__global__ __launch_bounds__(256)
void fft384(const void* in, float2* out, const int* DTp, int srcExt,
            const void* aux1, const void* aux2,
            const int* FLAGp, const void* dcwp, float2* outk)
{
    __shared__ float2 tw[384];
    __shared__ float2 stage[NLINE * SP];
    __shared__ float2 work[4][384];
    const int tid = threadIdx.x;
    const int dt = (srcExt || MODE) ? *DTp : 0;
    for (int j = tid; j < 384; j += 256) {
        float s, c;
        sincosf(-6.283185307179586f * (float)j / 384.0f, &s, &c);
        tw[j] = make_float2(c, s);
    }
    const int img = blockIdx.x / 48;
    const int t0  = (blockIdx.x % 48) * NLINE;
    const size_t base = (size_t)img * NPIX;
    float2* dst = out + base;

    if (AXIS == 0) {
        if (MODE == 1) {
            const float2* rim = (const float2*)aux1;
            const size_t rbase = (size_t)(img >> 4) * NPIX;
            for (int f = tid; f < NLINE*384; f += 256) {
                int l = f / 384, n = f - l*384;
                size_t pix = (size_t)(t0 + l)*384 + n;
                stage[l*SP + n] = cmul(rim[rbase + pix], loadc2(aux2, dt, base + pix));
            }
        } else {
            for (int f = tid; f < NLINE*384; f += 256) {
                int l = f / 384, n = f - l*384;
                stage[l*SP + n] = loadc2(in, dt, base + (size_t)(t0 + l)*384 + n);
            }
        }
    } else {
        for (int f = tid; f < NLINE*384; f += 256) {
            int l = f & 7, n = f >> 3;
            stage[l*SP + n] = loadc2(in, dt, base + (size_t)n*384 + (t0 + l));
        }
    }
    __syncthreads();
    const int g    = tid >> 6;
    const int lane = tid & 63;
    float2* w = work[g];
    const float SCALE = 0.05103103630798288f;
    for (int it = 0; it < 2; ++it) {
        const int l = it*4 + g;
        #pragma unroll
        for (int m = 0; m < 6; ++m) {
            int n = lane + 64*m;
            float2 v = stage[l*SP + n];
            float sgn = (n & 1) ? -1.f : 1.f;
            int q = n / 3;
            int r3 = n - 3*q;
            w[r3*128 + q] = make_float2(v.x*sgn, v.y*sgn);
        }
        __syncthreads();
        #pragma unroll
        for (int s = 0; s < 7; ++s) {
            const int h = 64 >> s;
            const int tstep = 3 << s;
            const int j = lane & (h-1);
            const int i = ((lane & ~(h-1)) << 1) | j;
            float2 t = tw[j * tstep];
            if (DIR < 0) t.y = -t.y;
            #pragma unroll
            for (int n1 = 0; n1 < 3; ++n1) {
                float2* a = w + (n1 << 7);
                float2 u = a[i], v = a[i+h];
                float2 d = make_float2(u.x - v.x, u.y - v.y);
                a[i]   = make_float2(u.x + v.x, u.y + v.y);
                a[i+h] = cmul(d, t);
            }
            __syncthreads();
        }
        #pragma unroll
        for (int half = 0; half < 2; ++half) {
            int k2 = lane + 64*half;
            int r  = __brev((unsigned)k2) >> 25;
            float2 a0 = w[r], a1 = w[128 + r], a2 = w[256 + r];
            float2 t1 = tw[k2];
            float2 t2 = tw[(2*k2) % 384];
            float2 w3 = tw[128], w3b = tw[256];
            if (DIR < 0) { t1.y=-t1.y; t2.y=-t2.y; w3.y=-w3.y; w3b.y=-w3b.y; }
            float2 b1 = cmul(a1, t1), b2 = cmul(a2, t2);
            float2 X0 = make_float2(a0.x + b1.x + b2.x, a0.y + b1.y + b2.y);
            float2 c1 = cmul(w3, b1), c2 = cmul(w3b, b2);
            float2 X1 = make_float2(a0.x + c1.x + c2.x, a0.y + c1.y + c2.y);
            float2 d1 = cmul(w3b, b1), d2 = cmul(w3, b2);
            float2 X2 = make_float2(a0.x + d1.x + d2.x, a0.y + d1.y + d2.y);
            float sc = (k2 & 1) ? -SCALE : SCALE;
            stage[l*SP + k2      ] = make_float2(X0.x*sc, X0.y*sc);
            stage[l*SP + k2 + 128] = make_float2(X1.x*sc, X1.y*sc);
            stage[l*SP + k2 + 256] = make_float2(X2.x*sc, X2.y*sc);
        }
        __syncthreads();
    }
    if (AXIS == 0) {
        for (int f = tid; f < NLINE*384; f += 256) {
            int l = f / 384, n = f - l*384;
            dst[(size_t)(t0 + l)*384 + n] = stage[l*SP + n];
        }
    } else {
        if (MODE == 2) {
            const int fl = *FLAGp;
            const float dw = loads1(dcwp, dt, 0);
            const int bb = img >> 4;
            for (int f = tid; f < NLINE*384; f += 256) {
                int l = f & 7, n = f >> 3;
                int wcol = t0 + l;
                size_t pix = (size_t)n*384 + wcol;
                float2 v = stage[l*SP + n];
                int m;
                switch (fl) {
                    case 0:  m = ((const unsigned char*)aux2)[bb*384 + wcol] != 0; break;
                    case 4:  m = ((const unsigned short*)aux2)[bb*384 + wcol] != 0; break;
                    case 3:  m = ((const unsigned long long*)aux2)[bb*384 + wcol] != 0ULL; break;
                    default: m = ((const unsigned int*)aux2)[bb*384 + wcol] != 0u; break;
                }
                if (m) {
                    float2 r = loadc2(aux1, dt, base + pix);
                    v.x -= (v.x - r.x)*dw;
                    v.y -= (v.y - r.y)*dw;
                }
                dst[pix] = v;
                outk[base + pix] = v;
            }
        } else {
            for (int f = tid; f < NLINE*384; f += 256) {
                int l = f & 7, n = f >> 3;
                dst[(size_t)n*384 + (t0 + l)] = stage[l*SP + n];
            }
        }
    }
}

__global__ void detect_mask(const unsigned char* __restrict__ m, int* flag)
{
    __shared__ int sA, sB, sC, sD, sE;
    if (threadIdx.x == 0) { sA = sB = sC = sD = sE = 0; }
    __syncthreads();
    for (int i = threadIdx.x; i < 768; i += 256) {
        unsigned char v = m[i];
        if (v > 1) atomicOr(&sA, 1);
        if ((i & 3) && v) atomicOr(&sB, 1);
    }
    const unsigned short* m16 = (const unsigned short*)m;
    for (int i = threadIdx.x; i < 384; i += 256)
        if (!(i & 1) && m16[i]) atomicOr(&sC, 1);
    const unsigned int* m32 = (const unsigned int*)m;
    for (int i = threadIdx.x; i < 192; i += 256) {
        if ((i & 1) && m32[i]) atomicOr(&sD, 1);
        if (!(i & 1) && m32[i]) atomicOr(&sE, 1);
    }
    __syncthreads();
    if (threadIdx.x == 0) {
        int f;
        if (!sA) { if (sB) f = 0; else if (sD) f = 2; else f = 3; }
        else     { if (sC) f = 4; else if (sE) f = 2; else f = 3; }
        *flag = f;
    }
}

template<bool WITH_STATS>
__global__ __launch_bounds__(256)
void reduce_sens(const float2* __restrict__ xin, const void* __restrict__ sens,
                 float2* __restrict__ ximg, const int* DTp,
                 float* __restrict__ partials)
{
    const int dt = *DTp;
    const int b = blockIdx.y;
    const int p = blockIdx.x*256 + threadIdx.x;
    float2 acc = make_float2(0.f, 0.f);
    for (int c = 0; c < CC; ++c) {
        size_t o = ((size_t)(b*CC + c))*NPIX + p;
        float2 a = xin[o];
        float2 s = loadc2(sens, dt, o);
        acc.x += a.x*s.x + a.y*s.y;
        acc.y += a.y*s.x - a.x*s.y;
    }
    ximg[(size_t)b*NPIX + p] = acc;
    if (WITH_STATS) {
        float sx = acc.x, sy = acc.y, qx = acc.x*acc.x, qy = acc.y*acc.y;
        #pragma unroll
        for (int o = 32; o > 0; o >>= 1) {
            sx += __shfl_down(sx, o, 64); sy += __shfl_down(sy, o, 64);
            qx += __shfl_down(qx, o, 64); qy += __shfl_down(qy, o, 64);
        }
        __shared__ float red[4][4];
        const int wv = threadIdx.x >> 6, lane = threadIdx.x & 63;
        if (lane == 0) {
            red[wv][0] = sx; red[wv][1] = sy; red[wv][2] = qx; red[wv][3] = qy;
        }
        __syncthreads();
        if (threadIdx.x == 0) {
            float t0 = red[0][0]+red[1][0]+red[2][0]+red[3][0];
            float t1 = red[0][1]+red[1][1]+red[2][1]+red[3][1];
            float t2 = red[0][2]+red[1][2]+red[2][2]+red[3][2];
            float t3 = red[0][3]+red[1][3]+red[2][3]+red[3][3];
            float* dst = partials + ((size_t)b*576 + blockIdx.x)*4;
            dst[0] = t0; dst[1] = t1; dst[2] = t2; dst[3] = t3;
        }
    }
}

__global__ __launch_bounds__(256)
void stats_finalize(const float* __restrict__ partials, float* __restrict__ ms)
{
    const int b = blockIdx.x;
    const int tid = threadIdx.x;
    float sx=0.f, sy=0.f, qx=0.f, qy=0.f;
    for (int i = tid; i < 576; i += 256) {
        const float* p = partials + ((size_t)b*576 + i)*4;
        sx += p[0]; sy += p[1]; qx += p[2]; qy += p[3];
    }
    __shared__ float r0[256], r1[256], r2[256], r3[256];
    r0[tid]=sx; r1[tid]=sy; r2[tid]=qx; r3[tid]=qy;
    __syncthreads();
    for (int s = 128; s > 0; s >>= 1) {
        if (tid < s) {
            r0[tid]+=r0[tid+s]; r1[tid]+=r1[tid+s];
            r2[tid]+=r2[tid+s]; r3[tid]+=r3[tid+s];
        }
        __syncthreads();
    }
    if (tid == 0) {
        const float N = (float)NPIX;
        float var0 = (r2[0] - r0[0]*r0[0]/N) / (N - 1.f);
        float var1 = (r3[0] - r1[0]*r1[0]/N) / (N - 1.f);
        ms[(b*2+0)*2]   = r0[0]/N;
        ms[(b*2+0)*2+1] = sqrtf(var0);
        ms[(b*2+1)*2]   = r1[0]/N;
        ms[(b*2+1)*2+1] = sqrtf(var1);
    }
}

// ---------------------------------------------------------------------------
// conv v3: wave-synchronous + register-sliding windows + packed channels.
// 4 waves x 16 channels. conv1: lane owns 18x6 strip (54 lanes), 24 b64 reads
// per channel. conv2: lane owns 4-row column, 18 b32 reads per channel.
// ---------------------------------------------------------------------------
__global__ __launch_bounds__(256)
void conv_fused(const float2* __restrict__ ximg, const void* __restrict__ w1g,
                const void* __restrict__ b1g, const void* __restrict__ w2g,
                const void* __restrict__ b2g, const float* __restrict__ msg,
                float2* __restrict__ rim, const int* DTp)
{
    __shared__ float2 inP[20][21];
    __shared__ float w1s[1152];
    __shared__ float w2s[1152];
    __shared__ float b1s[64];
    __shared__ float hidw[4][18*20];
    __shared__ float2 accs[4][256];

    const int dt = *DTp;
    const int b = blockIdx.z, bx = blockIdx.x, by = blockIdx.y;
    const int tid = threadIdx.x;
    const int wv = tid >> 6, lane = tid & 63;

    for (int f = tid; f < 1152; f += 256) {
        w1s[f] = loads1(w1g, dt, f);
        w2s[f] = loads1(w2g, dt, f);
    }
    if (tid < 64) b1s[tid] = loads1(b1g, dt, tid);
    const float mean0 = msg[(b*2+0)*2], istd0 = 1.f/msg[(b*2+0)*2+1];
    const float mean1 = msg[(b*2+1)*2], istd1 = 1.f/msg[(b*2+1)*2+1];
    for (int f = tid; f < 400; f += 256) {
        int yy = f / 20, xx = f - yy*20;
        int gy = by*16 + yy - 2, gx = bx*16 + xx - 2;
        float a = 0.f, c = 0.f;
        if (gy >= 0 && gy < HH && gx >= 0 && gx < WW) {
            float2 v = ximg[(size_t)b*NPIX + gy*WW + gx];
            a = (v.x - mean0)*istd0;
            c = (v.y - mean1)*istd1;
        }
        inP[yy][xx] = make_float2(a, c);
    }
    __syncthreads();

    float a0[4] = {0.f,0.f,0.f,0.f}, a1[4] = {0.f,0.f,0.f,0.f};
    float* hid = hidw[wv];

    // conv1 strip mapping (lanes 0..53): col 0..17, row-group 0..2 (6 rows)
    const int c1col = lane % 18;
    const int c1g   = lane / 18;           // 0..3; lane<54 -> 0..2
    const int c1y0  = 6 * c1g;
    // conv2 column mapping: col tx, 4 output rows ybase..ybase+3
    const int tx = lane & 15, ybase = (lane >> 4) * 4;

    for (int j = 0; j < 16; ++j) {
        const int o = wv*16 + j;
        const float* wa = &w1s[o*18];
        const float bo = b1s[o];
        if (c1g < 3) {
            float2 r0c0 = inP[c1y0][c1col],   r0c1 = inP[c1y0][c1col+1],   r0c2 = inP[c1y0][c1col+2];
            float2 r1c0 = inP[c1y0+1][c1col], r1c1 = inP[c1y0+1][c1col+1], r1c2 = inP[c1y0+1][c1col+2];
            #pragma unroll
            for (int rr = 0; rr < 6; ++rr) {
                float2 r2c0 = inP[c1y0+rr+2][c1col];
                float2 r2c1 = inP[c1y0+rr+2][c1col+1];
                float2 r2c2 = inP[c1y0+rr+2][c1col+2];
                float acc = bo
                    + wa[0]*r0c0.x + wa[1]*r0c1.x + wa[2]*r0c2.x
                    + wa[3]*r1c0.x + wa[4]*r1c1.x + wa[5]*r1c2.x
                    + wa[6]*r2c0.x + wa[7]*r2c1.x + wa[8]*r2c2.x
                    + wa[9]*r0c0.y  + wa[10]*r0c1.y + wa[11]*r0c2.y
                    + wa[12]*r1c0.y + wa[13]*r1c1.y + wa[14]*r1c2.y
                    + wa[15]*r2c0.y + wa[16]*r2c1.y + wa[17]*r2c2.y;
                int hy = c1y0 + rr;
                int gy = by*16 + hy - 1, gx = bx*16 + c1col - 1;
                hid[hy*20 + c1col] = (gy >= 0 && gy < HH && gx >= 0 && gx < WW)
                                   ? fmaxf(acc, 0.f) : 0.f;
                r0c0 = r1c0; r0c1 = r1c1; r0c2 = r1c2;
                r1c0 = r2c0; r1c1 = r2c1; r1c2 = r2c2;
            }
        }
        __builtin_amdgcn_wave_barrier();
        {
            const float* w2a = &w2s[o*9];
            const float* w2b = &w2s[576 + o*9];
            float h00 = hid[ybase*20 + tx],     h01 = hid[ybase*20 + tx+1],     h02 = hid[ybase*20 + tx+2];
            float h10 = hid[(ybase+1)*20 + tx], h11 = hid[(ybase+1)*20 + tx+1], h12 = hid[(ybase+1)*20 + tx+2];
            #pragma unroll
            for (int r = 0; r < 4; ++r) {
                float h20 = hid[(ybase+r+2)*20 + tx];
                float h21 = hid[(ybase+r+2)*20 + tx+1];
                float h22 = hid[(ybase+r+2)*20 + tx+2];
                a0[r] += w2a[0]*h00 + w2a[1]*h01 + w2a[2]*h02
                       + w2a[3]*h10 + w2a[4]*h11 + w2a[5]*h12
                       + w2a[6]*h20 + w2a[7]*h21 + w2a[8]*h22;
                a1[r] += w2b[0]*h00 + w2b[1]*h01 + w2b[2]*h02
                       + w2b[3]*h10 + w2b[4]*h11 + w2b[5]*h12
                       + w2b[6]*h20 + w2b[7]*h21 + w2b[8]*h22;
                h00 = h10; h01 = h11; h02 = h12;
                h10 = h20; h11 = h21; h12 = h22;
            }
        }
        __builtin_amdgcn_wave_barrier();
    }
    #pragma unroll
    for (int r = 0; r < 4; ++r)
        accs[wv][(ybase + r)*16 + tx] = make_float2(a0[r], a1[r]);
    __syncthreads();
    {
        const int p = tid;
        float s0 = loads1(b2g, dt, 0), s1 = loads1(b2g, dt, 1);
        #pragma unroll
        for (int wvi = 0; wvi < 4; ++wvi) {
            s0 += accs[wvi][p].x;
            s1 += accs[wvi][p].y;
        }
        const float std0 = msg[(b*2+0)*2+1], std1 = msg[(b*2+1)*2+1];
        int ty = p >> 4, txx = p & 15;
        rim[(size_t)b*NPIX + (by*16+ty)*WW + (bx*16+txx)]
            = make_float2(s0*std0 + mean0, s1*std1 + mean1);
    }
}

__global__ __launch_bounds__(384)
void predictor(const float2* __restrict__ kimg, const void* __restrict__ wmp,
               const void* __restrict__ bmp, float* __restrict__ prob,
               float* __restrict__ outp, const int* DTp)
{
    const int dt = *DTp;
    const int b = blockIdx.x, w = threadIdx.x;
    float s0 = 0.f, s1 = 0.f;
    for (int h = 0; h < HH; ++h) {
        float2 v = kimg[((size_t)b*HH + h)*WW + w];
        s0 += v.x; s1 += v.y;
    }
    float logit = (s0*loads1(wmp,dt,0) + s1*loads1(wmp,dt,1)) * (1.0f/384.0f)
                + loads1(bmp,dt,0);
    __shared__ float red[8];
    float m = logit;
    for (int o = 32; o > 0; o >>= 1) m = fmaxf(m, __shfl_down(m, o, 64));
    int wid = w >> 6, lane = w & 63;
    if (lane == 0) red[wid] = m;
    __syncthreads();
    if (w == 0) { float mm = red[0]; for (int i = 1; i < 6; ++i) mm = fmaxf(mm, red[i]); red[6] = mm; }
    __syncthreads();
    m = red[6];
    float e = expf(logit - m);
    float s = e;
    for (int o = 32; o > 0; o >>= 1) s += __shfl_down(s, o, 64);
    __syncthreads();
    if (lane == 0) red[wid] = s;
    __syncthreads();
    if (w == 0) { float ss = 0.f; for (int i = 0; i < 6; ++i) ss += red[i]; red[7] = ss; }
    __syncthreads();
    float pr = e / red[7];
    prob[b*WW + w] = pr;
    outp[b*WW + w] = pr;
}

__global__ __launch_bounds__(384)
void update_mask_k(const float* __restrict__ prob, const void* __restrict__ cmask,
                   const void* __restrict__ add_list, const void* __restrict__ itp,
                   float* __restrict__ outm, const int* DTp)
{
    const int dt = *DTp;
    const int b = blockIdx.x, w = threadIdx.x;
    __shared__ float p[384];
    float cm = loads1(cmask, dt, b*WW + w);
    float pv = prob[b*WW + w] * (1.0f - cm);
    p[w] = pv;
    __syncthreads();
    int rank = 0;
    for (int i = 0; i < 384; ++i) {
        float q = p[i];
        rank += (q > pv) || (q == pv && i < w);
    }
    int it = flex_int1(itp);
    if (it < 0 || it > 7) it = 0;
    int addn = flex_int_arr(add_list, b*8 + it);
    float val = cm + ((rank < addn) ? 1.0f : 0.0f);
    outm[b*WW + w] = val;
}

// ---------------------------------------------------------------------------
extern "C" void kernel_launch(void* const* d_in, const int* in_sizes, int n_in,
                              void* d_out, int out_size, void* d_ws, size_t ws_size,
                              hipStream_t stream)
{
    const void* src  = d_in[0];
    const void* tgt  = d_in[1];
    const void* mask = d_in[2];
    const void* sens = d_in[3];
    const void* itp  = d_in[4];
    const void* cmask= d_in[5];
    const void* addl = d_in[7];
    const void* dcw  = d_in[8];
    const void* w1   = d_in[9];
    const void* b1   = d_in[10];
    const void* w2   = d_in[11];
    const void* b2   = d_in[12];
    const void* wmp  = d_in[13];
    const void* bmp  = d_in[14];
    float* out = (float*)d_out;

    float* ws = (float*)d_ws;
    const size_t OFF_XIMG = 9437184;
    const size_t OFF_RIM  = OFF_XIMG + 589824;
    const size_t OFF_MS   = OFF_RIM  + 589824;
    const size_t OFF_PROB = OFF_MS + 8;
    const size_t OFF_FLAG = OFF_PROB + 768;
    const size_t OFF_DT   = OFF_FLAG + 4;
    const size_t OFF_PART = OFF_DT + 4;

    float2* A    = (float2*)ws;
    float2* XIMG = (float2*)(ws + OFF_XIMG);
    float2* RIM  = (float2*)(ws + OFF_RIM);
    float*  MS   = ws + OFF_MS;
    float*  PROB = ws + OFF_PROB;
    int*    FLAG = (int*)(ws + OFF_FLAG);
    int*    DT   = (int*)(ws + OFF_DT);
    float*  PART = ws + OFF_PART;

    const int gBig   = (BB*CC)*48;
    const int gSmall = BB*48;

    detect_dtype<<<1, 256, 0, stream>>>((const unsigned*)src, DT);
    detect_mask<<<1, 256, 0, stream>>>((const unsigned char*)mask, FLAG);

    fft384<-1,0,0><<<gBig, 256, 0, stream>>>(src, A, DT, 1, nullptr, nullptr, nullptr, nullptr, nullptr);
    fft384<-1,1,0><<<gBig, 256, 0, stream>>>(A, A, DT, 0, nullptr, nullptr, nullptr, nullptr, nullptr);
    reduce_sens<true><<<dim3((NPIX/256), BB), 256, 0, stream>>>(A, sens, XIMG, DT, PART);
    stats_finalize<<<BB, 256, 0, stream>>>(PART, MS);

    conv_fused<<<dim3(24,24,BB), 256, 0, stream>>>(XIMG, w1, b1, w2, b2, MS, RIM, DT);

    fft384<1,0,1><<<gBig, 256, 0, stream>>>(nullptr, A, DT, 0, RIM, sens, nullptr, nullptr, nullptr);
    fft384<1,1,2><<<gBig, 256, 0, stream>>>(A, A, DT, 0, tgt, mask, FLAG, dcw, (float2*)out);

    fft384<-1,0,0><<<gBig, 256, 0, stream>>>(A, A, DT, 0, nullptr, nullptr, nullptr, nullptr, nullptr);
    fft384<-1,1,0><<<gBig, 256, 0, stream>>>(A, A, DT, 0, nullptr, nullptr, nullptr, nullptr, nullptr);
    reduce_sens<false><<<dim3((NPIX/256), BB), 256, 0, stream>>>(A, sens, XIMG, DT, nullptr);

    fft384<1,0,0><<<gSmall, 256, 0, stream>>>(XIMG, XIMG, DT, 0, nullptr, nullptr, nullptr, nullptr, nullptr);
    fft384<1,1,0><<<gSmall, 256, 0, stream>>>(XIMG, XIMG, DT, 0, nullptr, nullptr, nullptr, nullptr, nullptr);

    predictor<<<BB, 384, 0, stream>>>(XIMG, wmp, bmp, PROB, out + 9437184 + 768, DT);
    update_mask_k<<<BB, 384, 0, stream>>>(PROB, cmask, addl, itp, out + 9437184, DT);
}